// Round 5
// baseline (119.023 us; speedup 1.0000x reference)
//
#include <hip/hip_runtime.h>

namespace {
constexpr int N_ = 8, C_ = 32, H_ = 256, W_ = 512, DISP_ = 25;
constexpr int CH_STRIDE = H_ * W_;  // elements between channels / disparities
}

// 4-way disparity-split kernel: 512 threads/block = one (n,h) row.
//   t = tid & 127 -> 4 output columns (w0 = 4t)
//   g = tid >> 7  -> disparity group (wave-uniform):
//     G0: i in [0,7)   G1: [7,13)   G2: [13,19)   G3: [19,25)
// Per-thread: acc[<=7][4] (28) + 3 y-float4 (12) + x (4) + addr ~15 => ~60
// VGPRs -> 6-8 waves/SIMD (round-4 post-mortem: 3 waves/SIMD gave only 42%
// VALUBusy; latency-bound). No double-buffer (round-3: dbuf spilled).
//
// y window base per group: b = w0 + OFF, OFF = {4, 0, -8, -12}  (mult of 4).
// ywin[m] = y[b + m], m = cw + 12 - OFF - i, compile-time in [0,12).
// Each float4 sub-window is either fully in [0,W) or fully OOB (base mult of
// 4); clamped (garbage) windows only feed epilogue-zeroed outputs.
template <int G>
__device__ __forceinline__ void disp_body(const float* __restrict__ xp,
                                          const float* __restrict__ yp,
                                          float* __restrict__ op,
                                          const int* yoff, int w0) {
  constexpr int I0 = (G == 0) ? 0 : (G == 1) ? 7 : (G == 2) ? 13 : 19;
  constexpr int NI = (G == 0) ? 7 : 6;
  constexpr int OFF = (G == 0) ? 4 : (G == 1) ? 0 : (G == 2) ? -8 : -12;

  float acc[NI][4];
#pragma unroll
  for (int il = 0; il < NI; ++il)
#pragma unroll
    for (int cw = 0; cw < 4; ++cw) acc[il][cw] = 0.0f;

#pragma unroll 1
  for (int c = 0; c < C_; ++c) {
    float4 yv[3];
#pragma unroll
    for (int k = 0; k < 3; ++k)
      yv[k] = *reinterpret_cast<const float4*>(yp + yoff[k]);
    const float4 xv = *reinterpret_cast<const float4*>(xp);

    const float xs[4] = {xv.x, xv.y, xv.z, xv.w};
    const float ywin[12] = {yv[0].x, yv[0].y, yv[0].z, yv[0].w,
                            yv[1].x, yv[1].y, yv[1].z, yv[1].w,
                            yv[2].x, yv[2].y, yv[2].z, yv[2].w};

#pragma unroll
    for (int il = 0; il < NI; ++il) {
#pragma unroll
      for (int cw = 0; cw < 4; ++cw) {
        acc[il][cw] += fabsf(xs[cw] - ywin[cw + 12 - OFF - (I0 + il)]);
      }
    }

    xp += CH_STRIDE;
    yp += CH_STRIDE;
  }

  // Epilogue: zero out-of-overlap (w,i) pairs, coalesced float4 stores.
#pragma unroll
  for (int il = 0; il < NI; ++il) {
    const int i = I0 + il;
    const int j0 = w0 - i + 12;  // y column used by cw=0
    float4 v;
    v.x = ((unsigned)(j0 + 0) < (unsigned)W_) ? acc[il][0] : 0.0f;
    v.y = ((unsigned)(j0 + 1) < (unsigned)W_) ? acc[il][1] : 0.0f;
    v.z = ((unsigned)(j0 + 2) < (unsigned)W_) ? acc[il][2] : 0.0f;
    v.w = ((unsigned)(j0 + 3) < (unsigned)W_) ? acc[il][3] : 0.0f;
    *reinterpret_cast<float4*>(op + (size_t)i * CH_STRIDE) = v;
  }
}

__global__ __launch_bounds__(512, 6) void rescost_kernel(
    const float* __restrict__ x, const float* __restrict__ y,
    float* __restrict__ out) {
  const int tid = threadIdx.x;
  const int t = tid & 127;   // column group
  const int g = tid >> 7;    // disparity group (wave-uniform)
  const int r = blockIdx.x;  // row in [0, N*H)
  const int n = r >> 8;      // H = 256
  const int h = r & (H_ - 1);
  const int w0 = t << 2;

  // 3 clamped 16B-aligned y-window offsets; base = w0 + OFF[g].
  const int off_tab[4] = {4, 0, -8, -12};
  const int ybase = w0 + off_tab[g];
  int yoff[3];
#pragma unroll
  for (int k = 0; k < 3; ++k) {
    int idx = ybase + 4 * k;
    idx = idx < 0 ? 0 : idx;
    idx = idx > (W_ - 4) ? (W_ - 4) : idx;
    yoff[k] = idx;
  }

  const size_t row_base = ((size_t)n * C_ * H_ + (size_t)h) * W_;
  const float* xp = x + row_base + w0;
  const float* yp = y + row_base;
  float* op = out + ((size_t)n * DISP_ * H_ + (size_t)h) * W_ + w0;

  if (g == 0)
    disp_body<0>(xp, yp, op, yoff, w0);
  else if (g == 1)
    disp_body<1>(xp, yp, op, yoff, w0);
  else if (g == 2)
    disp_body<2>(xp, yp, op, yoff, w0);
  else
    disp_body<3>(xp, yp, op, yoff, w0);
}

extern "C" void kernel_launch(void* const* d_in, const int* in_sizes, int n_in,
                              void* d_out, int out_size, void* d_ws, size_t ws_size,
                              hipStream_t stream) {
  const float* x = (const float*)d_in[0];
  const float* y = (const float*)d_in[1];
  float* out = (float*)d_out;
  dim3 grid(N_ * H_);  // one (n,h) row per block
  dim3 block(512);
  hipLaunchKernelGGL(rescost_kernel, grid, block, 0, stream, x, y, out);
}